// Round 9
// baseline (7041.666 us; speedup 1.0000x reference)
//
#include <hip/hip_runtime.h>

#define NPTS   8192
#define NBATCH 16
#define NGROUP 512
#define GSIZE  32
#define BIGF   1e10f
#define NBLK   4          // fps blocks per batch (split path)
#define FPT    256        // fps threads per block
#define PPT    8          // points per thread = 8192/NBLK/FPT

typedef unsigned long long u64;

#define WS_REP_OFF  0
#define WS_WS4_OFF  (32 * 1024)
#define WS_EX_OFF   (32 * 1024 + 2 * 1024 * 1024)
#define WS_NEED     (WS_EX_OFF + (size_t)NBATCH * NGROUP * NBLK * 4 * 8)

// DPP max on a packed u64 key: shift both 32-bit halves with the same ctrl,
// compare-select. bound_ctrl=true injects key=0 which loses vs any real
// candidate (val>=0, distinct indices), so it's inert. (Proven rounds 6-8.)
template <int CTRL>
__device__ __forceinline__ u64 dpp_max_u64(u64 k) {
    const unsigned lo  = (unsigned)k;
    const unsigned hi  = (unsigned)(k >> 32);
    const unsigned slo = (unsigned)__builtin_amdgcn_update_dpp(0, (int)lo, CTRL, 0xF, 0xF, true);
    const unsigned shi = (unsigned)__builtin_amdgcn_update_dpp(0, (int)hi, CTRL, 0xF, 0xF, true);
    const u64 s = ((u64)shi << 32) | slo;
    return s > k ? s : k;
}

__device__ __forceinline__ u64 umax64(u64 a, u64 b) { return a > b ? a : b; }

// static-index 8-way select tree (keeps arrays in registers; rule #20)
#define SEL8(arr, jj) ({                          \
    float _a0 = ((jj) & 1) ? arr[1] : arr[0];     \
    float _a1 = ((jj) & 1) ? arr[3] : arr[2];     \
    float _a2 = ((jj) & 1) ? arr[5] : arr[4];     \
    float _a3 = ((jj) & 1) ? arr[7] : arr[6];     \
    float _b0 = ((jj) & 2) ? _a1 : _a0;           \
    float _b1 = ((jj) & 2) ? _a3 : _a2;           \
    ((jj) & 4) ? _b1 : _b0; })

// ---------------------------------------------------------------------------
// Prepack: xyz of every point as float4 (coalesced 16B loads downstream) and
// zero the fps exchange region (must happen EVERY launch: graph replays don't
// re-poison, and the exchange protocol needs clear TOP bits).
// 512 blocks x 256 thr = 131072 threads; exchange = 131072 u64.
// ---------------------------------------------------------------------------
__global__ __launch_bounds__(256) void prepack_kernel(const float* __restrict__ pc,
                                                      float4* __restrict__ ws4,
                                                      u64* __restrict__ ex) {
    const int i = blockIdx.x * 256 + threadIdx.x;     // 0 .. 131071
    const float* s = pc + (size_t)i * 6;
    ws4[i] = make_float4(s[0], s[1], s[2], 0.0f);
    ex[i]  = 0ull;
}

// ---------------------------------------------------------------------------
// FPS, split across NBLK blocks per batch (64 blocks total -> 4x less VALU
// issue per CU on the serial path). Per iteration:
//  - each block: per-thread dist update over its 2048 pts (registers only),
//    packed-u64 DPP wave argmax, winning lane deposits {key, coords} in LDS,
//    4-wave tree -> block winner.
//  - cross-block: block winner {coords relaxed, key|TOP release} into a 128B
//    exchange line; all threads acquire-poll the 4 keys, tree-max -> next
//    `last` + its coords (so NO point-cloud LDS copy is needed at all).
// Values are written once; any lane exits the poll only when all 4 keys are
// final => every lane/block computes the identical winner. Exchange is
// zeroed by prepack each launch. Key order == (max dist, lowest idx) ==
// jnp.argmax tie-break; arithmetic per point unchanged from passing rounds.
// ---------------------------------------------------------------------------
__global__ __launch_bounds__(FPT) void fps_split_kernel(const float4* __restrict__ ws4,
                                                        u64* __restrict__ ex,
                                                        int* __restrict__ rep) {
    const int bid  = blockIdx.x;
    const int xcd  = bid & 7;                 // presumed XCD (heuristic only)
    const int s    = bid >> 3;                // 0..7
    const int b    = xcd * 2 + (s >> 2);      // batch: 2 batches per XCD
    const int blk  = s & 3;                   // block-in-batch 0..3
    const int t    = threadIdx.x;
    const int w    = t >> 6;

    __shared__ __align__(16) u64 wk[2][4][4]; // [parity][wave][{key, xy, z, pad}]
    __shared__ int lrep[NGROUP];

    const float4* base4 = ws4 + ((size_t)b << 13);
    const int pbase = blk * (NPTS / NBLK) + t * PPT;

    float px[PPT], py[PPT], pz[PPT], dmin[PPT];
#pragma unroll
    for (int j = 0; j < PPT; ++j) {
        const float4 P = base4[pbase + j];
        px[j] = P.x; py[j] = P.y; pz[j] = P.z;
        dmin[j] = BIGF;
    }

    u64* exb = ex + (size_t)b * NGROUP * (NBLK * 4);

    const float4 L0 = base4[0];
    float Lx = L0.x, Ly = L0.y, Lz = L0.z;
    int last = 0;

    for (int k = 0;; ++k) {
        if (blk == 0 && t == 0) lrep[k] = last;
        if (k == NGROUP - 1) break;

        float bv = -1.0f;
        int   bi = 0;
#pragma unroll
        for (int j = 0; j < PPT; ++j) {
            const float dx = __fsub_rn(px[j], Lx);
            const float dy = __fsub_rn(py[j], Ly);
            const float dz = __fsub_rn(pz[j], Lz);
            // ((dx^2 + dy^2) + dz^2), no FMA -> matches numpy fp32 (verified)
            const float d = __fadd_rn(__fadd_rn(__fmul_rn(dx, dx),
                                                __fmul_rn(dy, dy)),
                                      __fmul_rn(dz, dz));
            const float dm = fminf(dmin[j], d);
            dmin[j] = dm;
            if (dm > bv) { bv = dm; bi = pbase + j; }   // strict > keeps lowest idx
        }

        const u64 mykey = ((u64)__float_as_uint(bv) << 13) | (unsigned)(8191 - bi);
        u64 r = mykey;
        r = dpp_max_u64<0x111>(r);   // row_shr:1
        r = dpp_max_u64<0x112>(r);   // row_shr:2
        r = dpp_max_u64<0x114>(r);   // row_shr:4
        r = dpp_max_u64<0x118>(r);   // row_shr:8
        r = dpp_max_u64<0x142>(r);   // row_bcast:15
        r = dpp_max_u64<0x143>(r);   // row_bcast:31 -> lane 63 = wave max
        const unsigned wlo = (unsigned)__builtin_amdgcn_readlane((int)(unsigned)r, 63);
        const unsigned whi = (unsigned)__builtin_amdgcn_readlane((int)(unsigned)(r >> 32), 63);
        const u64 wkey = ((u64)whi << 32) | wlo;

        const int buf = k & 1;                    // parity dbuf -> 1 barrier/iter
        if (mykey == wkey) {                      // exactly one lane per wave
            const int jj = bi - pbase;            // 0..7
            const float cx = SEL8(px, jj);
            const float cy = SEL8(py, jj);
            const float cz = SEL8(pz, jj);
            wk[buf][w][0] = wkey;
            wk[buf][w][1] = ((u64)__float_as_uint(cy) << 32) | __float_as_uint(cx);
            wk[buf][w][2] = (u64)__float_as_uint(cz);
        }
        __syncthreads();

        // block winner: tree over 4 wave entries, coord-carry
        u64 bk  = wk[buf][0][0];
        u64 bxy = wk[buf][0][1];
        u64 bz  = wk[buf][0][2];
#pragma unroll
        for (int ww = 1; ww < 4; ++ww) {
            const u64 kk = wk[buf][ww][0];
            const bool gt = kk > bk;
            const u64 nxy = wk[buf][ww][1];
            const u64 nz  = wk[buf][ww][2];
            bk  = gt ? kk  : bk;
            bxy = gt ? nxy : bxy;
            bz  = gt ? nz  : bz;
        }

        // cross-block exchange: coords relaxed, key|TOP release; acquire-poll
        u64* slot = exb + (size_t)k * (NBLK * 4);
        if (t == 0) {
            __hip_atomic_store(slot + blk * 4 + 1, bxy, __ATOMIC_RELAXED, __HIP_MEMORY_SCOPE_AGENT);
            __hip_atomic_store(slot + blk * 4 + 2, bz,  __ATOMIC_RELAXED, __HIP_MEMORY_SCOPE_AGENT);
            __hip_atomic_store(slot + blk * 4 + 0, bk | 0x8000000000000000ull,
                               __ATOMIC_RELEASE, __HIP_MEMORY_SCOPE_AGENT);
        }
        u64 k0, k1, k2, k3;
        for (;;) {
            k0 = __hip_atomic_load(slot + 0,  __ATOMIC_ACQUIRE, __HIP_MEMORY_SCOPE_AGENT);
            k1 = __hip_atomic_load(slot + 4,  __ATOMIC_ACQUIRE, __HIP_MEMORY_SCOPE_AGENT);
            k2 = __hip_atomic_load(slot + 8,  __ATOMIC_ACQUIRE, __HIP_MEMORY_SCOPE_AGENT);
            k3 = __hip_atomic_load(slot + 12, __ATOMIC_ACQUIRE, __HIP_MEMORY_SCOPE_AGENT);
            if ((k0 & k1 & k2 & k3) >> 63) break;
            __builtin_amdgcn_s_sleep(1);
        }
        int wi = 0; u64 wbk = k0;
        if (k1 > wbk) { wbk = k1; wi = 1; }
        if (k2 > wbk) { wbk = k2; wi = 2; }
        if (k3 > wbk) { wbk = k3; wi = 3; }
        const u64 wxy = __hip_atomic_load(slot + wi * 4 + 1, __ATOMIC_RELAXED, __HIP_MEMORY_SCOPE_AGENT);
        const u64 wz  = __hip_atomic_load(slot + wi * 4 + 2, __ATOMIC_RELAXED, __HIP_MEMORY_SCOPE_AGENT);
        last = 8191 - (int)(wbk & 0x1FFFull);
        Lx = __uint_as_float((unsigned)wxy);
        Ly = __uint_as_float((unsigned)(wxy >> 32));
        Lz = __uint_as_float((unsigned)wz);
    }

    if (blk == 0) {
        __syncthreads();                          // block-uniform condition: legal
        for (int j = t; j < NGROUP; j += FPT)
            rep[b * NGROUP + j] = lrep[j];
    }
}

// ---------------------------------------------------------------------------
// Fallback FPS (round-7 verbatim, 537us, proven): used if ws_size too small
// for the exchange region.
// ---------------------------------------------------------------------------
__global__ __launch_bounds__(512) void fps_mono_kernel(const float* __restrict__ pc,
                                                       int* __restrict__ rep) {
    const int b    = blockIdx.x;
    const int t    = threadIdx.x;
    const int lane = t & 63;
    const int w    = t >> 6;

    __shared__ float4 sp[NPTS];
    __shared__ __align__(16) u64 keys[2][8];
    __shared__ int lrep[NGROUP];

    const float* base = pc + (size_t)b * NPTS * 6;

    float px[16], py[16], pz[16], dmin[16];
#pragma unroll
    for (int j = 0; j < 16; ++j) {
        const int p = t * 16 + j;
        const float x = base[p * 6 + 0];
        const float y = base[p * 6 + 1];
        const float z = base[p * 6 + 2];
        px[j] = x; py[j] = y; pz[j] = z;
        sp[p] = make_float4(x, y, z, 0.0f);
        dmin[j] = BIGF;
    }
    __syncthreads();

    int last = 0;
    for (int k = 0; k < NGROUP; ++k) {
        if (t == 0) lrep[k] = last;
        if (k == NGROUP - 1) break;

        const float4 L = sp[last];

        float bv = -1.0f;
        int   bi = 0;
#pragma unroll
        for (int j = 0; j < 16; ++j) {
            const float dx = __fsub_rn(px[j], L.x);
            const float dy = __fsub_rn(py[j], L.y);
            const float dz = __fsub_rn(pz[j], L.z);
            const float d = __fadd_rn(__fadd_rn(__fmul_rn(dx, dx),
                                                __fmul_rn(dy, dy)),
                                      __fmul_rn(dz, dz));
            const float dm = fminf(dmin[j], d);
            dmin[j] = dm;
            if (dm > bv) { bv = dm; bi = t * 16 + j; }
        }

        u64 key = ((u64)__float_as_uint(bv) << 13) | (unsigned)(8191 - bi);
        key = dpp_max_u64<0x111>(key);
        key = dpp_max_u64<0x112>(key);
        key = dpp_max_u64<0x114>(key);
        key = dpp_max_u64<0x118>(key);
        key = dpp_max_u64<0x142>(key);
        key = dpp_max_u64<0x143>(key);

        const int buf = k & 1;
        if (lane == 63) keys[buf][w] = key;
        __syncthreads();

        const ulonglong2* kp = (const ulonglong2*)keys[buf];
        const ulonglong2 c0 = kp[0], c1 = kp[1], c2 = kp[2], c3 = kp[3];
        const u64 best = umax64(umax64(umax64(c0.x, c0.y), umax64(c1.x, c1.y)),
                                umax64(umax64(c2.x, c2.y), umax64(c3.x, c3.y)));
        last = 8191 - (int)(best & 0x1FFFull);
    }

    __syncthreads();
    for (int j = t; j < NGROUP; j += 512)
        rep[b * NGROUP + j] = lrep[j];
}

// ---------------------------------------------------------------------------
// Kernel 2: 32-NN per sampled center + gathers (unchanged, passing).
// ---------------------------------------------------------------------------
__global__ __launch_bounds__(256) void knn_kernel(const float* __restrict__ pc,
                                                  const float4* __restrict__ ws4,
                                                  const int* __restrict__ rep,
                                                  float* __restrict__ out) {
    const int tid  = threadIdx.x;
    const int lane = tid & 63;
    const int w    = tid >> 6;
    const int q    = blockIdx.x * 4 + w;
    const int b    = q >> 9;

    const float*  base  = pc  + (size_t)b * NPTS * 6;
    const float4* base4 = ws4 + ((size_t)b << 13);
    const int     r     = rep[q];

    const float4 Q = base4[r];
    const float qxf = Q.x, qyf = Q.y, qzf = Q.z;
    const double qx = (double)qxf, qy = (double)qyf, qz = (double)qzf;

    const double DINF = __longlong_as_double(0x7ff0000000000000LL);
    double vd = DINF;  int vi = 0x7fffffff;
    double taud = DINF; int taui = 0x7fffffff;

    for (int i = 0; i < NPTS / 64; ++i) {
        const int p = i * 64 + lane;
        const float4 T = base4[p];
        const double dx = qx - (double)T.x;
        const double dy = qy - (double)T.y;
        const double dz = qz - (double)T.z;
        const double d2 = dx * dx + dy * dy + dz * dz;

        const bool acc = (d2 < taud) || (d2 == taud && p < taui);
        const unsigned long long mask0 = __ballot(acc);
        unsigned long long mask = mask0;
        while (mask) {
            const int l = __ffsll(mask) - 1;
            mask &= mask - 1;
            const double xd = __shfl(d2, l);
            const int    xi = __shfl(p, l);
            const double pd = __shfl_up(vd, 1);
            const int    pi = __shfl_up(vi, 1);
            const bool ltp = (lane > 0) && ((xd < pd) || (xd == pd && xi < pi));
            const bool ltc = (xd < vd) || (xd == vd && xi < vi);
            const double nvd = ltp ? pd : (ltc ? xd : vd);
            const int    nvi = ltp ? pi : (ltc ? xi : vi);
            vd = nvd; vi = nvi;
        }
        if (mask0) {
            taud = __shfl(vd, 31);
            taui = __shfl(vi, 31);
        }
    }

    const size_t NBH = (size_t)NBATCH * NGROUP * GSIZE * 6;
    const size_t CEN = (size_t)NBATCH * NGROUP * 6;

    if (lane == 0) {
#pragma unroll
        for (int c = 0; c < 6; ++c)
            out[NBH + (size_t)q * 6 + c] = base[r * 6 + c];
    }
    if (lane < GSIZE) {
        const int n = vi;
        out[NBH + CEN + (size_t)q * GSIZE + lane] = (float)n;

        const float* np_ = base + (size_t)n * 6;
        const size_t o = ((size_t)q * GSIZE + lane) * 6;
        out[o + 0] = __fsub_rn(np_[0], qxf);
        out[o + 1] = __fsub_rn(np_[1], qyf);
        out[o + 2] = __fsub_rn(np_[2], qzf);
        out[o + 3] = np_[3];
        out[o + 4] = np_[4];
        out[o + 5] = np_[5];
    }
}

extern "C" void kernel_launch(void* const* d_in, const int* in_sizes, int n_in,
                              void* d_out, int out_size, void* d_ws, size_t ws_size,
                              hipStream_t stream) {
    const float* pc  = (const float*)d_in[0];
    float*       out = (float*)d_out;
    int*         rep = (int*)((char*)d_ws + WS_REP_OFF);
    float4*      ws4 = (float4*)((char*)d_ws + WS_WS4_OFF);
    u64*         ex  = (u64*)((char*)d_ws + WS_EX_OFF);

    prepack_kernel<<<NBATCH * NPTS / 256, 256, 0, stream>>>(pc, ws4, ex);

    if (ws_size >= WS_NEED)
        fps_split_kernel<<<NBATCH * NBLK, FPT, 0, stream>>>(ws4, ex, rep);
    else
        fps_mono_kernel<<<NBATCH, 512, 0, stream>>>(pc, rep);

    knn_kernel<<<NBATCH * NGROUP / 4, 256, 0, stream>>>(pc, ws4, rep, out);
}

// Round 10
// 787.238 us; speedup vs baseline: 8.9448x; 8.9448x over previous
//
#include <hip/hip_runtime.h>

#define NPTS   8192
#define NBATCH 16
#define NGROUP 512
#define GSIZE  32
#define BIGF   1e10f

typedef unsigned long long u64;
typedef float f32x2 __attribute__((ext_vector_type(2)));

// Packed fp32 ops via inline asm (VOP3P, IEEE-rn per half — bit-identical to
// the scalar v_add_f32/v_mul_f32 sequence). Round 7 showed ext_vector math
// scalarizes; this forces the packed encoding.
__device__ __forceinline__ f32x2 pk_add(f32x2 a, f32x2 b) {
    f32x2 d;
    asm("v_pk_add_f32 %0, %1, %2" : "=v"(d) : "v"(a), "v"(b));
    return d;
}
__device__ __forceinline__ f32x2 pk_mul(f32x2 a, f32x2 b) {
    f32x2 d;
    asm("v_pk_mul_f32 %0, %1, %2" : "=v"(d) : "v"(a), "v"(b));
    return d;
}

// DPP f32 max chain step (values >= 0, bound_ctrl=true injects 0 -> inert).
template <int CTRL>
__device__ __forceinline__ float dpp_maxf(float x) {
    const int s = __builtin_amdgcn_update_dpp(0, __float_as_int(x), CTRL, 0xF, 0xF, true);
    return fmaxf(x, __int_as_float(s));
}
// DPP u32 min chain step (invalid lanes contribute old=INT_MAX -> inert).
template <int CTRL>
__device__ __forceinline__ unsigned dpp_minu(unsigned x) {
    const unsigned s = (unsigned)__builtin_amdgcn_update_dpp(0x7FFFFFFF, (int)x, CTRL, 0xF, 0xF, false);
    return x < s ? x : s;
}

__device__ __forceinline__ u64 umax64(u64 a, u64 b) { return a > b ? a : b; }

// ---------------------------------------------------------------------------
// Prepack: xyz of every point as float4 (coalesced 16B loads in knn).
// ---------------------------------------------------------------------------
__global__ __launch_bounds__(256) void prepack_kernel(const float* __restrict__ pc,
                                                      float4* __restrict__ ws4) {
    const int i = blockIdx.x * 256 + threadIdx.x;     // 0 .. 131071
    const float* s = pc + (size_t)i * 6;
    ws4[i] = make_float4(s[0], s[1], s[2], 0.0f);
}

// ---------------------------------------------------------------------------
// Kernel 1: farthest point sampling. One block per batch, 512 threads
// (8 waves, round-7 proven shape), 16 points per thread as 8 f32x2 pairs.
// Round-10 change: packed-fp32 distance math (asm v_pk_*) + value-only max3
// tracking, index recovered once per iteration:
//   wave max value: 6x DPP f32 max -> readlane 63 (SGPR broadcast, no LDS)
//   wave lowest matching index: per-lane scan (dmin==WV) + 6x DPP u32 min
// Selection = (max value, lowest index) == jnp.argmax. Arithmetic bits
// unchanged: x+(-L) == x-L, pk ops are IEEE-rn, same ((dx^2+dy^2)+dz^2).
// Cross-wave: 8 packed u64 keys in LDS read as 4x ulonglong2, tree max.
// ---------------------------------------------------------------------------
__global__ __launch_bounds__(512) void fps_kernel(const float* __restrict__ pc,
                                                  int* __restrict__ rep) {
    const int b    = blockIdx.x;
    const int t    = threadIdx.x;
    const int lane = t & 63;
    const int w    = t >> 6;

    __shared__ float4 sp[NPTS];                      // 128 KB
    __shared__ __align__(16) u64 keys[2][8];
    __shared__ int lrep[NGROUP];                     // 2 KB

    const float* base = pc + (size_t)b * NPTS * 6;

    f32x2 px[8], py[8], pz[8], dmin[8];
#pragma unroll
    for (int j = 0; j < 8; ++j) {
        const int p0 = t * 16 + 2 * j;
        const float x0 = base[p0 * 6 + 0], y0 = base[p0 * 6 + 1], z0 = base[p0 * 6 + 2];
        const float x1 = base[p0 * 6 + 6], y1 = base[p0 * 6 + 7], z1 = base[p0 * 6 + 8];
        px[j] = (f32x2){x0, x1};
        py[j] = (f32x2){y0, y1};
        pz[j] = (f32x2){z0, z1};
        sp[p0]     = make_float4(x0, y0, z0, 0.0f);
        sp[p0 + 1] = make_float4(x1, y1, z1, 0.0f);
        dmin[j] = (f32x2){BIGF, BIGF};
    }
    __syncthreads();

    const int tb = t * 16;
    int last = 0;
    for (int k = 0; k < NGROUP; ++k) {
        if (t == 0) lrep[k] = last;
        if (k == NGROUP - 1) break;

        const float4 L = sp[last];                   // one ds_read_b128, broadcast
        const f32x2 nLx = (f32x2){-L.x, -L.x};
        const f32x2 nLy = (f32x2){-L.y, -L.y};
        const f32x2 nLz = (f32x2){-L.z, -L.z};

        float bv = -1.0f;
#pragma unroll
        for (int j = 0; j < 8; ++j) {
            const f32x2 dx = pk_add(px[j], nLx);     // x + (-L) == x - L exactly
            const f32x2 dy = pk_add(py[j], nLy);
            const f32x2 dz = pk_add(pz[j], nLz);
            const f32x2 xx = pk_mul(dx, dx);
            const f32x2 yy = pk_mul(dy, dy);
            const f32x2 zz = pk_mul(dz, dz);
            const f32x2 d  = pk_add(pk_add(xx, yy), zz);   // ((x^2+y^2)+z^2)
            f32x2 dm;
            dm.x = fminf(dmin[j].x, d.x);
            dm.y = fminf(dmin[j].y, d.y);
            dmin[j] = dm;
            bv = fmaxf(bv, fmaxf(dm.x, dm.y));       // v_max3_f32
        }

        // wave max value (DPP chain, lane 63 accumulates) -> SGPR broadcast
        float m = bv;
        m = dpp_maxf<0x111>(m);   // row_shr:1
        m = dpp_maxf<0x112>(m);   // row_shr:2
        m = dpp_maxf<0x114>(m);   // row_shr:4
        m = dpp_maxf<0x118>(m);   // row_shr:8
        m = dpp_maxf<0x142>(m);   // row_bcast:15
        m = dpp_maxf<0x143>(m);   // row_bcast:31 -> lane 63 = wave max
        const float WV = __uint_as_float((unsigned)__builtin_amdgcn_readlane(__float_as_int(m), 63));

        // lowest local index with dmin == WV (UINT_MAX if none), then wave min
        unsigned cand = 0xFFFFFFFFu;
#pragma unroll
        for (int j = 0; j < 8; ++j) {
            const unsigned c0 = (dmin[j].x == WV) ? (unsigned)(tb + 2 * j)     : 0xFFFFFFFFu;
            const unsigned c1 = (dmin[j].y == WV) ? (unsigned)(tb + 2 * j + 1) : 0xFFFFFFFFu;
            cand = min(cand, min(c0, c1));           // v_min3_u32
        }
        unsigned c = cand;
        c = dpp_minu<0x111>(c);
        c = dpp_minu<0x112>(c);
        c = dpp_minu<0x114>(c);
        c = dpp_minu<0x118>(c);
        c = dpp_minu<0x142>(c);
        c = dpp_minu<0x143>(c);                      // lane 63 = wave lowest idx

        const int buf = k & 1;                       // parity dbuf -> 1 barrier/iter
        if (lane == 63)
            keys[buf][w] = ((u64)__float_as_uint(WV) << 13)
                         | (unsigned)(8191 - (int)c);
        __syncthreads();

        const ulonglong2* kp = (const ulonglong2*)keys[buf];   // 4x ds_read_b128
        const ulonglong2 k0 = kp[0], k1 = kp[1], k2 = kp[2], k3 = kp[3];
        const u64 best = umax64(umax64(umax64(k0.x, k0.y), umax64(k1.x, k1.y)),
                                umax64(umax64(k2.x, k2.y), umax64(k3.x, k3.y)));
        last = 8191 - (int)(best & 0x1FFFull);
    }

    __syncthreads();                                 // lrep visibility
    for (int j = t; j < NGROUP; j += 512)            // one coalesced write-out
        rep[b * NGROUP + j] = lrep[j];
}

// ---------------------------------------------------------------------------
// Kernel 2: 32-NN per sampled center + gathers. One wave per query,
// 256-thread blocks. Scan reads prepacked float4 (coalesced 16B, L2-resident).
// d2 in fp64 difference form (bit-robust true ranking; passed rounds 3,5-9).
// Top-32 as lane-distributed sorted list, lower-index tie-break.
// ---------------------------------------------------------------------------
__global__ __launch_bounds__(256) void knn_kernel(const float* __restrict__ pc,
                                                  const float4* __restrict__ ws4,
                                                  const int* __restrict__ rep,
                                                  float* __restrict__ out) {
    const int tid  = threadIdx.x;
    const int lane = tid & 63;
    const int w    = tid >> 6;
    const int q    = blockIdx.x * 4 + w;       // 0 .. 8191
    const int b    = q >> 9;

    const float*  base  = pc  + (size_t)b * NPTS * 6;
    const float4* base4 = ws4 + ((size_t)b << 13);
    const int     r     = rep[q];

    const float4 Q = base4[r];
    const float qxf = Q.x, qyf = Q.y, qzf = Q.z;
    const double qx = (double)qxf, qy = (double)qyf, qz = (double)qzf;

    const double DINF = __longlong_as_double(0x7ff0000000000000LL);
    double vd = DINF;  int vi = 0x7fffffff;    // distributed sorted list entry
    double taud = DINF; int taui = 0x7fffffff; // current 32nd element (lane 31)

    for (int i = 0; i < NPTS / 64; ++i) {
        const int p = i * 64 + lane;
        const float4 T = base4[p];             // coalesced 16B
        const double dx = qx - (double)T.x;
        const double dy = qy - (double)T.y;
        const double dz = qz - (double)T.z;
        const double d2 = dx * dx + dy * dy + dz * dz;   // no cancellation

        const bool acc = (d2 < taud) || (d2 == taud && p < taui);
        const unsigned long long mask0 = __ballot(acc);
        unsigned long long mask = mask0;
        while (mask) {
            const int l = __ffsll(mask) - 1;
            mask &= mask - 1;
            const double xd = __shfl(d2, l);
            const int    xi = __shfl(p, l);
            const double pd = __shfl_up(vd, 1);
            const int    pi = __shfl_up(vi, 1);
            const bool ltp = (lane > 0) && ((xd < pd) || (xd == pd && xi < pi));
            const bool ltc = (xd < vd) || (xd == vd && xi < vi);
            const double nvd = ltp ? pd : (ltc ? xd : vd);
            const int    nvi = ltp ? pi : (ltc ? xi : vi);
            vd = nvd; vi = nvi;
        }
        if (mask0) {                           // wave-uniform: tau unchanged if no accept
            taud = __shfl(vd, 31);
            taui = __shfl(vi, 31);
        }
    }

    // ---- outputs ----
    const size_t NBH = (size_t)NBATCH * NGROUP * GSIZE * 6;   // neighborhood elems
    const size_t CEN = (size_t)NBATCH * NGROUP * 6;           // center elems

    if (lane == 0) {
#pragma unroll
        for (int c = 0; c < 6; ++c)
            out[NBH + (size_t)q * 6 + c] = base[r * 6 + c];
    }
    if (lane < GSIZE) {
        const int n = vi;                      // lane-sorted: position == lane
        out[NBH + CEN + (size_t)q * GSIZE + lane] = (float)n;

        const float* np_ = base + (size_t)n * 6;
        const size_t o = ((size_t)q * GSIZE + lane) * 6;
        out[o + 0] = __fsub_rn(np_[0], qxf);
        out[o + 1] = __fsub_rn(np_[1], qyf);
        out[o + 2] = __fsub_rn(np_[2], qzf);
        out[o + 3] = np_[3];
        out[o + 4] = np_[4];
        out[o + 5] = np_[5];
    }
}

extern "C" void kernel_launch(void* const* d_in, const int* in_sizes, int n_in,
                              void* d_out, int out_size, void* d_ws, size_t ws_size,
                              hipStream_t stream) {
    const float* pc  = (const float*)d_in[0];
    float*       out = (float*)d_out;
    int*         rep = (int*)d_ws;                              // 32 KB
    float4*      ws4 = (float4*)((char*)d_ws + 32 * 1024);      // 2 MB

    prepack_kernel<<<NBATCH * NPTS / 256, 256, 0, stream>>>(pc, ws4);
    fps_kernel<<<NBATCH, 512, 0, stream>>>(pc, rep);
    knn_kernel<<<NBATCH * NGROUP / 4, 256, 0, stream>>>(pc, ws4, rep, out);
}

// Round 11
// 653.746 us; speedup vs baseline: 10.7712x; 1.2042x over previous
//
#include <hip/hip_runtime.h>

#define NPTS   8192
#define NBATCH 16
#define NGROUP 512
#define GSIZE  32
#define BIGF   1e10f

typedef unsigned long long u64;

// DPP max on a packed u64 key (round-7 proven): shift both 32-bit halves,
// compare-select. bound_ctrl=true injects key=0 which loses vs any real
// candidate (val>=0, distinct indices), so it's inert.
template <int CTRL>
__device__ __forceinline__ u64 dpp_max_u64(u64 k) {
    const unsigned lo  = (unsigned)k;
    const unsigned hi  = (unsigned)(k >> 32);
    const unsigned slo = (unsigned)__builtin_amdgcn_update_dpp(0, (int)lo, CTRL, 0xF, 0xF, true);
    const unsigned shi = (unsigned)__builtin_amdgcn_update_dpp(0, (int)hi, CTRL, 0xF, 0xF, true);
    const u64 s = ((u64)shi << 32) | slo;
    return s > k ? s : k;
}

__device__ __forceinline__ u64 umax64(u64 a, u64 b) { return a > b ? a : b; }

// wave-uniform 64-bit readlane (SALU path, no LDS pipe)
__device__ __forceinline__ u64 rdlane64(u64 v, int l) {
    const unsigned lo = (unsigned)__builtin_amdgcn_readlane((int)(unsigned)v, l);
    const unsigned hi = (unsigned)__builtin_amdgcn_readlane((int)(unsigned)(v >> 32), l);
    return ((u64)hi << 32) | lo;
}

// ---------------------------------------------------------------------------
// Kernel 1: farthest point sampling — round-7 body verbatim (537us proven),
// plus fused prepack: the preamble also writes xyz as float4 to ws4 for knn.
// ---------------------------------------------------------------------------
__global__ __launch_bounds__(512) void fps_kernel(const float* __restrict__ pc,
                                                  int* __restrict__ rep,
                                                  float4* __restrict__ ws4) {
    const int b    = blockIdx.x;
    const int t    = threadIdx.x;
    const int lane = t & 63;
    const int w    = t >> 6;

    __shared__ float4 sp[NPTS];                      // 128 KB
    __shared__ __align__(16) u64 keys[2][8];
    __shared__ int lrep[NGROUP];                     // 2 KB

    const float* base = pc + (size_t)b * NPTS * 6;
    float4* w4 = ws4 + ((size_t)b << 13);

    float px[16], py[16], pz[16], dmin[16];
#pragma unroll
    for (int j = 0; j < 16; ++j) {
        const int p = t * 16 + j;
        const float x = base[p * 6 + 0];
        const float y = base[p * 6 + 1];
        const float z = base[p * 6 + 2];
        px[j] = x; py[j] = y; pz[j] = z;
        const float4 f = make_float4(x, y, z, 0.0f);
        sp[p] = f;
        w4[p] = f;                                   // fused prepack
        dmin[j] = BIGF;
    }
    __syncthreads();

    int last = 0;
    for (int k = 0; k < NGROUP; ++k) {
        if (t == 0) lrep[k] = last;
        if (k == NGROUP - 1) break;

        const float4 L = sp[last];                   // one ds_read_b128, broadcast

        float bv = -1.0f;
        int   bi = 0;
#pragma unroll
        for (int j = 0; j < 16; ++j) {
            const float dx = __fsub_rn(px[j], L.x);
            const float dy = __fsub_rn(py[j], L.y);
            const float dz = __fsub_rn(pz[j], L.z);
            // ((dx^2 + dy^2) + dz^2), no FMA -> matches numpy fp32 (verified)
            const float d = __fadd_rn(__fadd_rn(__fmul_rn(dx, dx),
                                                __fmul_rn(dy, dy)),
                                      __fmul_rn(dz, dz));
            const float dm = fminf(dmin[j], d);
            dmin[j] = dm;
            if (dm > bv) { bv = dm; bi = t * 16 + j; }   // strict > keeps lowest idx
        }

        u64 key = ((u64)__float_as_uint(bv) << 13) | (unsigned)(8191 - bi);
        key = dpp_max_u64<0x111>(key);   // row_shr:1
        key = dpp_max_u64<0x112>(key);   // row_shr:2
        key = dpp_max_u64<0x114>(key);   // row_shr:4
        key = dpp_max_u64<0x118>(key);   // row_shr:8
        key = dpp_max_u64<0x142>(key);   // row_bcast:15
        key = dpp_max_u64<0x143>(key);   // row_bcast:31 -> lane 63 = wave max

        const int buf = k & 1;                       // parity dbuf -> 1 barrier/iter
        if (lane == 63) keys[buf][w] = key;
        __syncthreads();

        const ulonglong2* kp = (const ulonglong2*)keys[buf];   // 4x ds_read_b128
        const ulonglong2 k0 = kp[0], k1 = kp[1], k2 = kp[2], k3 = kp[3];
        const u64 best = umax64(umax64(umax64(k0.x, k0.y), umax64(k1.x, k1.y)),
                                umax64(umax64(k2.x, k2.y), umax64(k3.x, k3.y)));
        last = 8191 - (int)(best & 0x1FFFull);
    }

    __syncthreads();                                 // lrep visibility
    for (int j = t; j < NGROUP; j += 512)            // one coalesced write-out
        rep[b * NGROUP + j] = lrep[j];
}

// ---------------------------------------------------------------------------
// Kernel 2: 32-NN per sampled center + gathers. One wave per query.
// Round-11 rework of the selection machinery (values/order unchanged):
//  - list key = f64 d2 bit pattern as u64 (positive doubles order as u64):
//    one v_cmp_lt_u64 replaces the f64 lex-compare chains. Exact-tie
//    index-break dropped (P[exact f64 tie] ~ 1e-8; prior rounds strict).
//  - candidate broadcast via readlane (SALU), candidate index is affine in
//    lane (i*128+l) -> computed, not shuffled. Insert: 3 bpermutes (shfl_up).
//  - 2 points/lane/iter: halves fixed per-iter costs, pipelines 2 loads;
//    tau refreshed between half-masks to cut the iter-0 flood.
// d2 math bit-identical: cvt_f64_f32 + dsub + mul/fma (contract on, as before).
// ---------------------------------------------------------------------------
__global__ __launch_bounds__(256) void knn_kernel(const float* __restrict__ pc,
                                                  const float4* __restrict__ ws4,
                                                  const int* __restrict__ rep,
                                                  float* __restrict__ out) {
    const int tid  = threadIdx.x;
    const int lane = tid & 63;
    const int w    = tid >> 6;
    const int q    = blockIdx.x * 4 + w;       // 0 .. 8191
    const int b    = q >> 9;

    const float*  base  = pc  + (size_t)b * NPTS * 6;
    const float4* base4 = ws4 + ((size_t)b << 13);
    const int     r     = rep[q];

    const float4 Q = base4[r];
    const float qxf = Q.x, qyf = Q.y, qzf = Q.z;
    const double qx = (double)qxf, qy = (double)qyf, qz = (double)qzf;

    const u64 INFB = 0x7ff0000000000000ull;
    u64 vk = INFB;  int vi = 0x7fffffff;       // lane-distributed sorted list
    u64 tauk = INFB;                           // 32nd element's key (uniform)

    for (int i = 0; i < NPTS / 128; ++i) {
        const int p0 = i * 128 + lane;
        const float4 T0 = base4[p0];
        const float4 T1 = base4[p0 + 64];

        const double dx0 = qx - (double)T0.x;
        const double dy0 = qy - (double)T0.y;
        const double dz0 = qz - (double)T0.z;
        const u64 kd0 = __double_as_longlong(dx0 * dx0 + dy0 * dy0 + dz0 * dz0);
        const double dx1 = qx - (double)T1.x;
        const double dy1 = qy - (double)T1.y;
        const double dz1 = qz - (double)T1.z;
        const u64 kd1 = __double_as_longlong(dx1 * dx1 + dy1 * dy1 + dz1 * dz1);

        u64 m0 = __ballot(kd0 < tauk);
        const u64 m1pre = __ballot(kd1 < tauk);

        if (m0 | m1pre) {
            while (m0) {
                const int l = __ffsll(m0) - 1;
                m0 &= m0 - 1;
                const u64 xk = rdlane64(kd0, l);   // SALU broadcast
                const int xi = i * 128 + l;        // affine: no shuffle
                const u64 pk = __shfl_up(vk, 1);
                const int pv = __shfl_up(vi, 1);
                const bool ltp = (lane > 0) && (xk < pk);
                const bool ltc = xk < vk;
                vk = ltp ? pk : (ltc ? xk : vk);
                vi = ltp ? pv : (ltc ? xi : vi);
            }
            tauk = rdlane64(vk, 31);               // refresh before half B
            u64 m1 = m1pre;
            while (m1) {
                const int l = __ffsll(m1) - 1;
                m1 &= m1 - 1;
                const u64 xk = rdlane64(kd1, l);
                if (xk < tauk) {                   // re-filter vs fresh tau
                    const int xi = i * 128 + 64 + l;
                    const u64 pk = __shfl_up(vk, 1);
                    const int pv = __shfl_up(vi, 1);
                    const bool ltp = (lane > 0) && (xk < pk);
                    const bool ltc = xk < vk;
                    vk = ltp ? pk : (ltc ? xk : vk);
                    vi = ltp ? pv : (ltc ? xi : vi);
                }
            }
            tauk = rdlane64(vk, 31);
        }
    }

    // ---- outputs ----
    const size_t NBH = (size_t)NBATCH * NGROUP * GSIZE * 6;   // neighborhood elems
    const size_t CEN = (size_t)NBATCH * NGROUP * 6;           // center elems

    if (lane == 0) {
#pragma unroll
        for (int c = 0; c < 6; ++c)
            out[NBH + (size_t)q * 6 + c] = base[r * 6 + c];
    }
    if (lane < GSIZE) {
        const int n = vi;                      // lane-sorted: position == lane
        out[NBH + CEN + (size_t)q * GSIZE + lane] = (float)n;

        const float* np_ = base + (size_t)n * 6;
        const size_t o = ((size_t)q * GSIZE + lane) * 6;
        out[o + 0] = __fsub_rn(np_[0], qxf);
        out[o + 1] = __fsub_rn(np_[1], qyf);
        out[o + 2] = __fsub_rn(np_[2], qzf);
        out[o + 3] = np_[3];
        out[o + 4] = np_[4];
        out[o + 5] = np_[5];
    }
}

extern "C" void kernel_launch(void* const* d_in, const int* in_sizes, int n_in,
                              void* d_out, int out_size, void* d_ws, size_t ws_size,
                              hipStream_t stream) {
    const float* pc  = (const float*)d_in[0];
    float*       out = (float*)d_out;
    int*         rep = (int*)d_ws;                              // 32 KB
    float4*      ws4 = (float4*)((char*)d_ws + 32 * 1024);      // 2 MB

    fps_kernel<<<NBATCH, 512, 0, stream>>>(pc, rep, ws4);
    knn_kernel<<<NBATCH * NGROUP / 4, 256, 0, stream>>>(pc, ws4, rep, out);
}